// Round 1
// baseline (285.237 us; speedup 1.0000x reference)
//
#include <hip/hip_runtime.h>

// ---------------------------------------------------------------------------
// MultiheadSelfAttention: B=2, S=2048, D=1024, H=16, DK=64
// cast->bf16 ; fused QKV GEMM (BK=64 XOR-swizzled staging, epilogue-LDS union,
// V transposed, Q scaled log2e/8) ; flash attention (key-split waves, no-max
// exp2 softmax, PV via K=16 MFMA from regs, XCD swizzle, BARRIER-FREE K-loop
// with per-wave private K/V LDS slices) ; output projection.
// ---------------------------------------------------------------------------

typedef __attribute__((ext_vector_type(8))) short bf16x8;   // 8 bf16
typedef __attribute__((ext_vector_type(4))) short bf16x4;   // 4 bf16
typedef __attribute__((ext_vector_type(4))) float f32x4;
typedef __attribute__((ext_vector_type(2))) unsigned int u32x2;

#define GK 1024
#define SEQ 2048
#define NHEAD 16
#define DKD 64
#define PADW 72      // padded LDS row stride (elems) for gemm epilogue tiles

#define MFMA32(a, b, c) __builtin_amdgcn_mfma_f32_16x16x32_bf16((a), (b), (c), 0, 0, 0)
#define MFMA16(a, b, c) __builtin_amdgcn_mfma_f32_16x16x16bf16_1k((a), (b), (c), 0, 0, 0)

#if __has_builtin(__builtin_amdgcn_exp2f)
#define EXP2(x) __builtin_amdgcn_exp2f(x)
#else
#define EXP2(x) exp2f(x)
#endif

// Q scale: (1/sqrt(64)) * log2(e), folded into the Q projection epilogue
#define QSCALE 0.18033688011f

static __device__ __forceinline__ unsigned short f2bf(float f) {
    unsigned int u = __float_as_uint(f);
    u += 0x7fffu + ((u >> 16) & 1u);     // RNE
    return (unsigned short)(u >> 16);
}

// pack two f32 -> two bf16 in one dword (a -> low half). round-half-up + v_perm.
static __device__ __forceinline__ unsigned int pack_bf2(float a, float b) {
    unsigned int ua = __float_as_uint(a) + 0x8000u;
    unsigned int ub = __float_as_uint(b) + 0x8000u;
    return __builtin_amdgcn_perm(ub, ua, 0x07060302u);  // [b.hi16, a.hi16]
}

// ---------------------------------------------------------------- fused casts
__global__ __launch_bounds__(256) void cast_all(const float* __restrict__ x,
                                                const float* __restrict__ wq,
                                                const float* __restrict__ wk,
                                                const float* __restrict__ wv,
                                                const float* __restrict__ wo,
                                                unsigned short* __restrict__ Xb,
                                                unsigned short* __restrict__ Wqkv,
                                                unsigned short* __restrict__ Wob) {
    const int bid = blockIdx.x;
    const float* src; unsigned short* dst; int off;
    if (bid < 4096)      { src = x;  dst = Xb;             off = bid; }
    else if (bid < 5120) { src = wq; dst = Wqkv;           off = bid - 4096; }
    else if (bid < 6144) { src = wk; dst = Wqkv + 1048576; off = bid - 5120; }
    else if (bid < 7168) { src = wv; dst = Wqkv + 2097152; off = bid - 6144; }
    else                 { src = wo; dst = Wob;            off = bid - 7168; }
    const int i = off * 1024 + threadIdx.x * 4;
    float4 v = *(const float4*)(src + i);
    u32x2 p; p.x = pack_bf2(v.x, v.y); p.y = pack_bf2(v.z, v.w);
    *(u32x2*)(dst + i) = p;
}

// ---------------------------------------------------------------- GEMM C = A * B^T
// BK=64 K-loop (16 barrier-pairs). LDS rows are 8 x 16B chunks, stored XOR-
// swizzled: LDS chunk c' of row r holds global chunk c'^(r&7) (staging permutes
// the per-lane GLOBAL address; LDS dest stays uniform+lane*16B as required by
// global_load_lds). Fragment reads un-swizzle with the same XOR -> banks spread
// across 8 groups (structural optimum). MODE 0: QKV epilogue via per-wave LDS
// scratch UNIONED with As/Bs (one barrier after K-loop). MODE 1: fp32 +bias.
template <int MODE, int BN>
__global__ __launch_bounds__(256) void gemm_bt(const unsigned short* __restrict__ A,
                                               const unsigned short* __restrict__ Bw,
                                               unsigned short* __restrict__ outb,
                                               float* __restrict__ outf,
                                               const float* __restrict__ bias) {
    constexpr int NJ = BN / 32;
    constexpr int LOOP_BYTES = 128 * 64 * 2 + BN * 64 * 2;
    constexpr int EPI_BYTES  = 4 * 64 * PADW * 2;
    constexpr int SMEM_BYTES = (MODE == 0)
        ? (LOOP_BYTES > EPI_BYTES ? LOOP_BYTES : EPI_BYTES)
        : LOOP_BYTES;
    __shared__ __align__(16) unsigned char SMEM[SMEM_BYTES];
    unsigned short* As = (unsigned short*)SMEM;            // [128][64] swizzled
    unsigned short* Bs = As + 128 * 64;                    // [BN][64] swizzled

    const int t    = threadIdx.x;
    const int lane = t & 63;
    const int w    = t >> 6;
    const int wm   = (w >> 1) * 64;
    const int wn   = (w & 1) * (BN / 2);
    const int bm0  = blockIdx.x * 128;
    const int bn0  = blockIdx.y * BN;
    const int lm   = lane & 15;
    const int lq   = lane >> 4;
    const int swzb = lm & 7;            // row&7 for all frag rows (row%16 == lm)

    const unsigned short* Ab = A + (size_t)bm0 * GK;
    const unsigned short* Bb = Bw + (size_t)bn0 * GK;

    f32x4 acc[4][NJ];
    const f32x4 Z4 = {0.f, 0.f, 0.f, 0.f};
#pragma unroll
    for (int i = 0; i < 4; i++)
#pragma unroll
        for (int j = 0; j < NJ; j++) acc[i][j] = Z4;

    const int q_uni = (t & ~63);

    for (int k0 = 0; k0 < GK; k0 += 64) {
        __syncthreads();
        // A: 128 rows x 8 chunks = 1024 chunks, 4 per thread
#pragma unroll
        for (int i = 0; i < 4; ++i) {
            int q  = i * 256 + t;
            int r  = q >> 3;
            int gc = (q & 7) ^ (r & 7);          // global col chunk (swizzle)
            int q0 = i * 256 + q_uni;
            __builtin_amdgcn_global_load_lds(
                (const __attribute__((address_space(1))) void*)(Ab + (size_t)r * GK + k0 + gc * 8),
                (__attribute__((address_space(3))) void*)(As + (size_t)q0 * 8),
                16, 0, 0);
        }
        // B: BN rows x 8 chunks, BN/32 per thread
#pragma unroll
        for (int i = 0; i < BN / 32; ++i) {
            int q  = i * 256 + t;
            int r  = q >> 3;
            int gc = (q & 7) ^ (r & 7);
            int q0 = i * 256 + q_uni;
            __builtin_amdgcn_global_load_lds(
                (const __attribute__((address_space(1))) void*)(Bb + (size_t)r * GK + k0 + gc * 8),
                (__attribute__((address_space(3))) void*)(Bs + (size_t)q0 * 8),
                16, 0, 0);
        }
        __syncthreads();

#pragma unroll
        for (int kk = 0; kk < 2; ++kk) {
            const int swz = ((kk * 4 + lq) ^ swzb) * 8;   // un-swizzled col elems
            bf16x8 af[4], bf[NJ];
#pragma unroll
            for (int i = 0; i < 4; i++)
                af[i] = *(const bf16x8*)(As + (wm + i * 16 + lm) * 64 + swz);
#pragma unroll
            for (int j = 0; j < NJ; j++)
                bf[j] = *(const bf16x8*)(Bs + (wn + j * 16 + lm) * 64 + swz);
#pragma unroll
            for (int i = 0; i < 4; i++)
#pragma unroll
                for (int j = 0; j < NJ; j++)
                    acc[i][j] = MFMA32(af[i], bf[j], acc[i][j]);
        }
    }

    if (MODE == 0) {
        __syncthreads();                         // all K-loop LDS reads retired
        unsigned short* E  = (unsigned short*)SMEM;   // union with As/Bs
        unsigned short* Ew = E + w * (64 * PADW);
        const int nbase = bn0 + wn;
        const int which = nbase >> 10;            // 0=Q 1=K 2=V
        const int hh    = (nbase & 1023) >> 6;
        if (which != 2) {
            const float sc = (which == 0) ? QSCALE : 1.0f;
#pragma unroll
            for (int i = 0; i < 4; i++)
#pragma unroll
                for (int j = 0; j < 4; j++)
#pragma unroll
                    for (int r = 0; r < 4; r++)
                        Ew[(i * 16 + lq * 4 + r) * PADW + j * 16 + lm] =
                            f2bf(acc[i][j][r] * sc);
            unsigned short* dst = outb + (size_t)which * 4194304;
#pragma unroll
            for (int rep = 0; rep < 8; ++rep) {
                const int mm = rep * 8 + (lane >> 3);
                const int d0 = (lane & 7) * 8;
                uint4 v = *(const uint4*)(Ew + mm * PADW + d0);
                const int m_g = bm0 + wm + mm;
                const int b = m_g >> 11, s = m_g & 2047;
                *(uint4*)(dst + (((size_t)(b * NHEAD + hh)) * SEQ + s) * DKD + d0) = v;
            }
        } else {
#pragma unroll
            for (int i = 0; i < 4; i++)
#pragma unroll
                for (int j = 0; j < 4; j++) {
                    u32x2 pk;
                    pk.x = pack_bf2(acc[i][j][0], acc[i][j][1]);
                    pk.y = pack_bf2(acc[i][j][2], acc[i][j][3]);
                    *(u32x2*)(Ew + (j * 16 + lm) * PADW + i * 16 + lq * 4) = pk;
                }
            unsigned short* dst = outb + (size_t)2 * 4194304;
#pragma unroll
            for (int rep = 0; rep < 8; ++rep) {
                const int nn = rep * 8 + (lane >> 3);
                const int mc = (lane & 7) * 8;
                uint4 v = *(const uint4*)(Ew + nn * PADW + mc);
                const int m_g = bm0 + wm + mc;
                const int b = m_g >> 11, s0 = m_g & 2047;
                *(uint4*)(dst + (((size_t)(b * NHEAD + hh)) * DKD + nn) * SEQ + s0) = v;
            }
        }
    } else {
#pragma unroll
        for (int i = 0; i < 4; i++) {
            const int mbase = bm0 + wm + i * 16 + lq * 4;
#pragma unroll
            for (int j = 0; j < NJ; j++) {
                const int n = bn0 + wn + j * 16 + lm;
#pragma unroll
                for (int r = 0; r < 4; r++)
                    outf[(size_t)(mbase + r) * 1024 + n] = acc[i][j][r] + bias[n];
            }
        }
    }
}

// ---------------------------------------------------------------- flash attention
// KEY-SPLIT: block = 64 q rows; each of 4 waves owns 16 keys of every 64-key
// tile. Q (B-operand) lives in regs; per iter each wave reads only 2 b128 (K)
// + 4 b64 (V) from LDS. S^T C-layout rows = this wave's keys; P -> PV directly
// from regs via K=16 MFMA. O/l are key-partial per wave; reduced through the
// retired KV LDS at the end. Grid 1024 = 8 XCD x 4 heads x 32 q-blocks.
//
// BARRIER-FREE MAIN LOOP: each wave stages its OWN K rows [16][72] and its own
// V key-columns [64][16] into a private double-buffered LDS slice (8704 B/wave,
// 34816 B total, unioned with the 36864 B epilogue scratch). No cross-wave LDS
// data flow until the epilogue -> zero __syncthreads in the K-loop, so the
// vmcnt(0)+lgkmcnt(0) barrier drain disappears and prefetched global loads
// stay in flight a full iteration. s_setprio(1) wraps the MFMA cluster (waves
// now free-run at different phases -> scheduler has something to arbitrate).
__global__ __launch_bounds__(256, 4) void attn_kernel(const unsigned short* __restrict__ Qg,
                                                      const unsigned short* __restrict__ Kg,
                                                      const unsigned short* __restrict__ Vtg,
                                                      unsigned short* __restrict__ Og) {
    // per-wave slice: buf b at w*4352 + b*2176 shorts; K [16][72] then V [64][16]
    __shared__ __align__(16) unsigned char SMEM[36864];

    const int id  = blockIdx.x;
    const int xcd = id & 7;
    const int j8  = id >> 3;                 // 0..127
    const int bh  = xcd * 4 + (j8 & 3);      // 4 heads per XCD
    const int qb  = j8 >> 2;                 // 0..31 (64-row q blocks)
    const unsigned short* Qp  = Qg  + ((size_t)bh * SEQ + qb * 64) * DKD;
    const unsigned short* Kp  = Kg  + (size_t)bh * SEQ * DKD;
    const unsigned short* Vtp = Vtg + (size_t)bh * DKD * SEQ;

    const int t    = threadIdx.x;
    const int lane = t & 63;
    const int w    = t >> 6;       // key-quarter owner
    const int lm   = lane & 15;
    const int kq   = lane >> 4;

    unsigned short* Wb = (unsigned short*)SMEM + w * 4352;

    const f32x4 Z4 = {0.f, 0.f, 0.f, 0.f};

    // Q B-frags for all 64 q rows (identical in all 4 waves), from global once
    bf16x8 aq[4][2];
#pragma unroll
    for (int c = 0; c < 4; ++c)
#pragma unroll
        for (int kk = 0; kk < 2; ++kk)
            aq[c][kk] = *(const bf16x8*)(Qp + (size_t)(c * 16 + lm) * DKD + kk * 32 + kq * 8);

    f32x4 o[4][4];                 // [q-chunk][d-chunk], partial over this wave's keys
    float ls[4];                   // in-lane l partial for q = c*16+lm
#pragma unroll
    for (int c = 0; c < 4; ++c) {
        ls[c] = 0.f;
#pragma unroll
        for (int dj = 0; dj < 4; ++dj) o[c][dj] = Z4;
    }

    // staging: wave-private. K: 16 rows x 64 d (4 lanes/row, 32B each);
    // V: 64 d-rows x this wave's 16 keys (1 lane/row, 32B each).
    const int krow = lane >> 2;               // 0..15
    const int kc   = (lane & 3) * 16;         // elem col within 64
    const unsigned short* KpW = Kp + (size_t)(w * 16 + krow) * DKD + kc;
    const unsigned short* VpW = Vtp + (size_t)lane * SEQ + w * 16;

    uint4 kreg0, kreg1, vreg0, vreg1;
    {   // tile 0 -> buf 0
        uint4 a0 = *(const uint4*)(KpW);
        uint4 a1 = *(const uint4*)(KpW + 8);
        uint4 b0 = *(const uint4*)(VpW);
        uint4 b1 = *(const uint4*)(VpW + 8);
        uint4* dk = (uint4*)(Wb + krow * 72 + kc); dk[0] = a0; dk[1] = a1;
        uint4* dv = (uint4*)(Wb + 1152 + lane * 16); dv[0] = b0; dv[1] = b1;
    }
    {   // prefetch tile 1
        const unsigned short* kp = KpW + (size_t)64 * DKD;
        kreg0 = *(const uint4*)(kp); kreg1 = *(const uint4*)(kp + 8);
        const unsigned short* vp = VpW + 64;
        vreg0 = *(const uint4*)(vp); vreg1 = *(const uint4*)(vp + 8);
    }

    for (int kt = 0; kt < 32; ++kt) {
        if (kt + 1 < 32) {
            unsigned short* Bn = Wb + ((kt + 1) & 1) * 2176;
            uint4* dk = (uint4*)(Bn + krow * 72 + kc);
            dk[0] = kreg0; dk[1] = kreg1;
            uint4* dv = (uint4*)(Bn + 1152 + lane * 16);
            dv[0] = vreg0; dv[1] = vreg1;
        }
        if (kt + 2 < 32) {
            const unsigned short* kp = KpW + (size_t)(kt + 2) * 64 * DKD;
            kreg0 = *(const uint4*)(kp); kreg1 = *(const uint4*)(kp + 8);
            const unsigned short* vp = VpW + (kt + 2) * 64;
            vreg0 = *(const uint4*)(vp); vreg1 = *(const uint4*)(vp + 8);
        }
        const unsigned short* Kc = Wb + (kt & 1) * 2176;
        const unsigned short* Vc = Kc + 1152;

        // S^T[this wave's 16 keys][64 q] = K Q^T : A = own K rows 0..15
        bf16x8 ak0 = *(const bf16x8*)(Kc + lm * 72 + kq * 8);
        bf16x8 ak1 = *(const bf16x8*)(Kc + lm * 72 + 32 + kq * 8);
        f32x4 s[4];
        __builtin_amdgcn_s_setprio(1);
#pragma unroll
        for (int c = 0; c < 4; ++c) {
            s[c] = MFMA32(ak0, aq[c][0], Z4);
            s[c] = MFMA32(ak1, aq[c][1], s[c]);
        }
        __builtin_amdgcn_s_setprio(0);

        // p = exp2(s); accumulate in-lane l (keys kq*4+r of this wave)
#pragma unroll
        for (int c = 0; c < 4; ++c) {
#pragma unroll
            for (int r = 0; r < 4; ++r) s[c][r] = EXP2(s[c][r]);
            ls[c] += (s[c][0] + s[c][1]) + (s[c][2] + s[c][3]);
        }

        // P C-layout == K=16 MFMA A-layout (lane: q=lm, keys kq*4+r)
        bf16x4 ap[4];
#pragma unroll
        for (int c = 0; c < 4; ++c) {
            u32x2 pk;
            pk.x = pack_bf2(s[c][0], s[c][1]);
            pk.y = pack_bf2(s[c][2], s[c][3]);
            ap[c] = __builtin_bit_cast(bf16x4, pk);
        }

        // O += P V over this wave's 16 keys
        __builtin_amdgcn_s_setprio(1);
#pragma unroll
        for (int dj = 0; dj < 4; ++dj) {
            bf16x4 bv = *(const bf16x4*)(Vc + (dj * 16 + lm) * 16 + kq * 4);
#pragma unroll
            for (int c = 0; c < 4; ++c)
                o[c][dj] = MFMA16(ap[c], bv, o[c][dj]);
        }
        __builtin_amdgcn_s_setprio(0);
    }

    // ---------------- cross-wave reduction through retired KV LDS ----------
    __syncthreads();
    float* Lf = (float*)SMEM;                 // 9216 floats available

    // l: reduce over quads in-wave, write per-wave partials Lf[w*64 + q]
#pragma unroll
    for (int c = 0; c < 4; ++c) {
        float v = ls[c];
        v += __shfl_xor(v, 16);
        v += __shfl_xor(v, 32);
        if (kq == 0) Lf[w * 64 + c * 16 + lm] = v;
    }
    __syncthreads();

    // each thread computes linv for the q-row it will store (rq = t>>2)
    const int rq = t >> 2;                    // 0..63
    const int dq = (t & 3) * 8;               // d offset within 32-chunk
    float li = (Lf[rq] + Lf[64 + rq]) + (Lf[128 + rq] + Lf[192 + rq]);
#if __has_builtin(__builtin_amdgcn_rcpf)
    li = __builtin_amdgcn_rcpf(li);
#else
    li = 1.0f / li;
#endif
    __syncthreads();                          // l reads done before overwrite

    const int b = bh >> 4, h = bh & 15;
    // O: two passes of 32 d-columns; Lo[w][q=64][d'=32] stride 36 (=9216 floats)
#pragma unroll
    for (int p = 0; p < 2; ++p) {
#pragma unroll
        for (int c = 0; c < 4; ++c)
#pragma unroll
            for (int djh = 0; djh < 2; ++djh) {
                const int dj = 2 * p + djh;
#pragma unroll
                for (int r = 0; r < 4; ++r)
                    Lf[(w * 64 + c * 16 + kq * 4 + r) * 36 + djh * 16 + lm] = o[c][dj][r];
            }
        __syncthreads();
        f32x4 a0 = Z4, a1 = Z4;
#pragma unroll
        for (int wp = 0; wp < 4; ++wp) {
            a0 += *(const f32x4*)(Lf + (wp * 64 + rq) * 36 + dq);
            a1 += *(const f32x4*)(Lf + (wp * 64 + rq) * 36 + dq + 4);
        }
        uint4 outv;
        outv.x = pack_bf2(a0[0] * li, a0[1] * li);
        outv.y = pack_bf2(a0[2] * li, a0[3] * li);
        outv.z = pack_bf2(a1[0] * li, a1[1] * li);
        outv.w = pack_bf2(a1[2] * li, a1[3] * li);
        *(uint4*)(Og + (((size_t)(b * SEQ + qb * 64 + rq)) * NHEAD + h) * DKD + p * 32 + dq) = outv;
        __syncthreads();
    }
}

// ---------------------------------------------------------------- launcher
extern "C" void kernel_launch(void* const* d_in, const int* in_sizes, int n_in,
                              void* d_out, int out_size, void* d_ws, size_t ws_size,
                              hipStream_t stream) {
    const float* x  = (const float*)d_in[0];
    const float* Wq = (const float*)d_in[1];
    const float* Wk = (const float*)d_in[2];
    const float* Wv = (const float*)d_in[3];
    const float* Wo = (const float*)d_in[4];
    const float* bo = (const float*)d_in[5];
    float* out = (float*)d_out;

    unsigned short* ws = (unsigned short*)d_ws;
    unsigned short* Xb   = ws;                       // [4096][1024]
    unsigned short* Wqkv = ws + 4194304;             // [3072][1024] (Wq|Wk|Wv)
    unsigned short* Wob  = ws + 7340032;             // [1024][1024]
    unsigned short* QKV  = ws + 8388608;             // Q,K:[b,h,s,d]; V:[b,h,d,s]
    unsigned short* Ob   = ws + 20971520;            // [4096][1024] = [b,s,h,d]

    cast_all<<<8192, 256, 0, stream>>>(x, Wq, Wk, Wv, Wo, Xb, Wqkv, Wob);
    gemm_bt<0, 128><<<dim3(32, 24), 256, 0, stream>>>(Xb, Wqkv, QKV, nullptr, nullptr);
    attn_kernel<<<1024, 256, 0, stream>>>(QKV, QKV + 4194304, QKV + 8388608, Ob);
    gemm_bt<1, 64><<<dim3(32, 16), 256, 0, stream>>>(Ob, Wob, nullptr, out, bo);
}

// Round 2
// 213.072 us; speedup vs baseline: 1.3387x; 1.3387x over previous
//
#include <hip/hip_runtime.h>

// ---------------------------------------------------------------------------
// MultiheadSelfAttention: B=2, S=2048, D=1024, H=16, DK=64
// cast->bf16 ; fused QKV GEMM (BK=64 XOR-swizzled staging, epilogue-LDS union,
// V transposed, Q scaled log2e/8) ; flash attention (key-split waves, no-max
// exp2 softmax, PAIRED PV via K=32 MFMA from regs, XCD swizzle) ; output proj.
// ---------------------------------------------------------------------------

typedef __attribute__((ext_vector_type(8))) short bf16x8;   // 8 bf16
typedef __attribute__((ext_vector_type(4))) short bf16x4;   // 4 bf16
typedef __attribute__((ext_vector_type(4))) float f32x4;
typedef __attribute__((ext_vector_type(2))) unsigned int u32x2;
typedef __attribute__((ext_vector_type(4))) unsigned int u32x4;

#define GK 1024
#define SEQ 2048
#define NHEAD 16
#define DKD 64
#define PADW 72      // padded LDS row stride (elems) for attn/epilogue tiles

#define MFMA32(a, b, c) __builtin_amdgcn_mfma_f32_16x16x32_bf16((a), (b), (c), 0, 0, 0)

#if __has_builtin(__builtin_amdgcn_exp2f)
#define EXP2(x) __builtin_amdgcn_exp2f(x)
#else
#define EXP2(x) exp2f(x)
#endif

// Q scale: (1/sqrt(64)) * log2(e), folded into the Q projection epilogue
#define QSCALE 0.18033688011f

static __device__ __forceinline__ unsigned short f2bf(float f) {
    unsigned int u = __float_as_uint(f);
    u += 0x7fffu + ((u >> 16) & 1u);     // RNE
    return (unsigned short)(u >> 16);
}

// pack two f32 -> two bf16 in one dword (a -> low half). round-half-up + v_perm.
static __device__ __forceinline__ unsigned int pack_bf2(float a, float b) {
    unsigned int ua = __float_as_uint(a) + 0x8000u;
    unsigned int ub = __float_as_uint(b) + 0x8000u;
    return __builtin_amdgcn_perm(ub, ua, 0x07060302u);  // [b.hi16, a.hi16]
}

// ---------------------------------------------------------------- fused casts
__global__ __launch_bounds__(256) void cast_all(const float* __restrict__ x,
                                                const float* __restrict__ wq,
                                                const float* __restrict__ wk,
                                                const float* __restrict__ wv,
                                                const float* __restrict__ wo,
                                                unsigned short* __restrict__ Xb,
                                                unsigned short* __restrict__ Wqkv,
                                                unsigned short* __restrict__ Wob) {
    const int bid = blockIdx.x;
    const float* src; unsigned short* dst; int off;
    if (bid < 4096)      { src = x;  dst = Xb;             off = bid; }
    else if (bid < 5120) { src = wq; dst = Wqkv;           off = bid - 4096; }
    else if (bid < 6144) { src = wk; dst = Wqkv + 1048576; off = bid - 5120; }
    else if (bid < 7168) { src = wv; dst = Wqkv + 2097152; off = bid - 6144; }
    else                 { src = wo; dst = Wob;            off = bid - 7168; }
    const int i = off * 1024 + threadIdx.x * 4;
    float4 v = *(const float4*)(src + i);
    u32x2 p; p.x = pack_bf2(v.x, v.y); p.y = pack_bf2(v.z, v.w);
    *(u32x2*)(dst + i) = p;
}

// ---------------------------------------------------------------- GEMM C = A * B^T
// BK=64 K-loop (16 barrier-pairs). LDS rows are 8 x 16B chunks, stored XOR-
// swizzled: LDS chunk c' of row r holds global chunk c'^(r&7) (staging permutes
// the per-lane GLOBAL address; LDS dest stays uniform+lane*16B as required by
// global_load_lds). Fragment reads un-swizzle with the same XOR -> banks spread
// across 8 groups (structural optimum). MODE 0: QKV epilogue via per-wave LDS
// scratch UNIONED with As/Bs (one barrier after K-loop). MODE 1: fp32 +bias.
template <int MODE, int BN>
__global__ __launch_bounds__(256) void gemm_bt(const unsigned short* __restrict__ A,
                                               const unsigned short* __restrict__ Bw,
                                               unsigned short* __restrict__ outb,
                                               float* __restrict__ outf,
                                               const float* __restrict__ bias) {
    constexpr int NJ = BN / 32;
    constexpr int LOOP_BYTES = 128 * 64 * 2 + BN * 64 * 2;
    constexpr int EPI_BYTES  = 4 * 64 * PADW * 2;
    constexpr int SMEM_BYTES = (MODE == 0)
        ? (LOOP_BYTES > EPI_BYTES ? LOOP_BYTES : EPI_BYTES)
        : LOOP_BYTES;
    __shared__ __align__(16) unsigned char SMEM[SMEM_BYTES];
    unsigned short* As = (unsigned short*)SMEM;            // [128][64] swizzled
    unsigned short* Bs = As + 128 * 64;                    // [BN][64] swizzled

    const int t    = threadIdx.x;
    const int lane = t & 63;
    const int w    = t >> 6;
    const int wm   = (w >> 1) * 64;
    const int wn   = (w & 1) * (BN / 2);
    const int bm0  = blockIdx.x * 128;
    const int bn0  = blockIdx.y * BN;
    const int lm   = lane & 15;
    const int lq   = lane >> 4;
    const int swzb = lm & 7;            // row&7 for all frag rows (row%16 == lm)

    const unsigned short* Ab = A + (size_t)bm0 * GK;
    const unsigned short* Bb = Bw + (size_t)bn0 * GK;

    f32x4 acc[4][NJ];
    const f32x4 Z4 = {0.f, 0.f, 0.f, 0.f};
#pragma unroll
    for (int i = 0; i < 4; i++)
#pragma unroll
        for (int j = 0; j < NJ; j++) acc[i][j] = Z4;

    const int q_uni = (t & ~63);

    for (int k0 = 0; k0 < GK; k0 += 64) {
        __syncthreads();
        // A: 128 rows x 8 chunks = 1024 chunks, 4 per thread
#pragma unroll
        for (int i = 0; i < 4; ++i) {
            int q  = i * 256 + t;
            int r  = q >> 3;
            int gc = (q & 7) ^ (r & 7);          // global col chunk (swizzle)
            int q0 = i * 256 + q_uni;
            __builtin_amdgcn_global_load_lds(
                (const __attribute__((address_space(1))) void*)(Ab + (size_t)r * GK + k0 + gc * 8),
                (__attribute__((address_space(3))) void*)(As + (size_t)q0 * 8),
                16, 0, 0);
        }
        // B: BN rows x 8 chunks, BN/32 per thread
#pragma unroll
        for (int i = 0; i < BN / 32; ++i) {
            int q  = i * 256 + t;
            int r  = q >> 3;
            int gc = (q & 7) ^ (r & 7);
            int q0 = i * 256 + q_uni;
            __builtin_amdgcn_global_load_lds(
                (const __attribute__((address_space(1))) void*)(Bb + (size_t)r * GK + k0 + gc * 8),
                (__attribute__((address_space(3))) void*)(Bs + (size_t)q0 * 8),
                16, 0, 0);
        }
        __syncthreads();

#pragma unroll
        for (int kk = 0; kk < 2; ++kk) {
            const int swz = ((kk * 4 + lq) ^ swzb) * 8;   // un-swizzled col elems
            bf16x8 af[4], bf[NJ];
#pragma unroll
            for (int i = 0; i < 4; i++)
                af[i] = *(const bf16x8*)(As + (wm + i * 16 + lm) * 64 + swz);
#pragma unroll
            for (int j = 0; j < NJ; j++)
                bf[j] = *(const bf16x8*)(Bs + (wn + j * 16 + lm) * 64 + swz);
#pragma unroll
            for (int i = 0; i < 4; i++)
#pragma unroll
                for (int j = 0; j < NJ; j++)
                    acc[i][j] = MFMA32(af[i], bf[j], acc[i][j]);
        }
    }

    if (MODE == 0) {
        __syncthreads();                         // all K-loop LDS reads retired
        unsigned short* E  = (unsigned short*)SMEM;   // union with As/Bs
        unsigned short* Ew = E + w * (64 * PADW);
        const int nbase = bn0 + wn;
        const int which = nbase >> 10;            // 0=Q 1=K 2=V
        const int hh    = (nbase & 1023) >> 6;
        if (which != 2) {
            const float sc = (which == 0) ? QSCALE : 1.0f;
#pragma unroll
            for (int i = 0; i < 4; i++)
#pragma unroll
                for (int j = 0; j < 4; j++)
#pragma unroll
                    for (int r = 0; r < 4; r++)
                        Ew[(i * 16 + lq * 4 + r) * PADW + j * 16 + lm] =
                            f2bf(acc[i][j][r] * sc);
            unsigned short* dst = outb + (size_t)which * 4194304;
#pragma unroll
            for (int rep = 0; rep < 8; ++rep) {
                const int mm = rep * 8 + (lane >> 3);
                const int d0 = (lane & 7) * 8;
                uint4 v = *(const uint4*)(Ew + mm * PADW + d0);
                const int m_g = bm0 + wm + mm;
                const int b = m_g >> 11, s = m_g & 2047;
                *(uint4*)(dst + (((size_t)(b * NHEAD + hh)) * SEQ + s) * DKD + d0) = v;
            }
        } else {
#pragma unroll
            for (int i = 0; i < 4; i++)
#pragma unroll
                for (int j = 0; j < 4; j++) {
                    u32x2 pk;
                    pk.x = pack_bf2(acc[i][j][0], acc[i][j][1]);
                    pk.y = pack_bf2(acc[i][j][2], acc[i][j][3]);
                    *(u32x2*)(Ew + (j * 16 + lm) * PADW + i * 16 + lq * 4) = pk;
                }
            unsigned short* dst = outb + (size_t)2 * 4194304;
#pragma unroll
            for (int rep = 0; rep < 8; ++rep) {
                const int nn = rep * 8 + (lane >> 3);
                const int mc = (lane & 7) * 8;
                uint4 v = *(const uint4*)(Ew + nn * PADW + mc);
                const int m_g = bm0 + wm + mc;
                const int b = m_g >> 11, s0 = m_g & 2047;
                *(uint4*)(dst + (((size_t)(b * NHEAD + hh)) * DKD + nn) * SEQ + s0) = v;
            }
        }
    } else {
#pragma unroll
        for (int i = 0; i < 4; i++) {
            const int mbase = bm0 + wm + i * 16 + lq * 4;
#pragma unroll
            for (int j = 0; j < NJ; j++) {
                const int n = bn0 + wn + j * 16 + lm;
#pragma unroll
                for (int r = 0; r < 4; r++)
                    outf[(size_t)(mbase + r) * 1024 + n] = acc[i][j][r] + bias[n];
            }
        }
    }
}

// ---------------------------------------------------------------- flash attention
// KEY-SPLIT: block = 64 q rows; each of 4 waves owns 16 keys of every 64-key
// tile. Q (B-operand) lives in regs; per iter each wave reads only 2 b128 (K)
// + 4 b64 (V) from LDS. S^T C-layout rows = this wave's keys. PV is PAIRED:
// two consecutive 64-key tiles are softmaxed, then one K=32 MFMA pass consumes
// both (k-axis permuted k = kq*8 + tile*4 + r; A = concat(pkE,pkO), B =
// concat(bvE,bvO) — both sides agree, so the contraction is exact). This
// replaces 32x MFMA16 with 16x MFMA32 per pair (-33% matrix-pipe issue).
// O/l are key-partial per wave; reduced through the retired KV LDS at the end.
// Grid 1024 = 8 XCD x 4 heads x 32 q-blocks.
__global__ __launch_bounds__(256, 3) void attn_kernel(const unsigned short* __restrict__ Qg,
                                                      const unsigned short* __restrict__ Kg,
                                                      const unsigned short* __restrict__ Vtg,
                                                      unsigned short* __restrict__ Og) {
    __shared__ __align__(16) unsigned short KV[2][2][64 * PADW];  // 36,864 B

    const int id  = blockIdx.x;
    const int xcd = id & 7;
    const int j8  = id >> 3;                 // 0..127
    const int bh  = xcd * 4 + (j8 & 3);      // 4 heads per XCD
    const int qb  = j8 >> 2;                 // 0..31 (64-row q blocks)
    const unsigned short* Qp  = Qg  + ((size_t)bh * SEQ + qb * 64) * DKD;
    const unsigned short* Kp  = Kg  + (size_t)bh * SEQ * DKD;
    const unsigned short* Vtp = Vtg + (size_t)bh * DKD * SEQ;

    const int t    = threadIdx.x;
    const int lane = t & 63;
    const int w    = t >> 6;       // key-quarter owner
    const int lm   = lane & 15;
    const int kq   = lane >> 4;

    const f32x4 Z4 = {0.f, 0.f, 0.f, 0.f};

    // Q B-frags for all 64 q rows (identical in all 4 waves), from global once
    bf16x8 aq[4][2];
#pragma unroll
    for (int c = 0; c < 4; ++c)
#pragma unroll
        for (int kk = 0; kk < 2; ++kk)
            aq[c][kk] = *(const bf16x8*)(Qp + (size_t)(c * 16 + lm) * DKD + kk * 32 + kq * 8);

    f32x4 o[4][4];                 // [q-chunk][d-chunk], partial over this wave's keys
    float ls[4];                   // in-lane l partial for q = c*16+lm
#pragma unroll
    for (int c = 0; c < 4; ++c) {
        ls[c] = 0.f;
#pragma unroll
        for (int dj = 0; dj < 4; ++dj) o[c][dj] = Z4;
    }

    // staging: K tile [64 key][64 d], V tile [64 d][64 key]; 2 uint4/thread each
    const int sr = t >> 2, sc = (t & 3) * 16;
    uint4 kreg0, kreg1, vreg0, vreg1;
    {   // tile 0 -> buf 0
        const unsigned short* kp = Kp + (size_t)sr * DKD + sc;
        const unsigned short* vp = Vtp + (size_t)sr * SEQ + sc;
        uint4 a0 = *(const uint4*)(kp), a1 = *(const uint4*)(kp + 8);
        uint4 b0 = *(const uint4*)(vp), b1 = *(const uint4*)(vp + 8);
        uint4* dk = (uint4*)(&KV[0][0][sr * PADW + sc]); dk[0] = a0; dk[1] = a1;
        uint4* dv = (uint4*)(&KV[0][1][sr * PADW + sc]); dv[0] = b0; dv[1] = b1;
    }
    {   // prefetch tile 1
        const unsigned short* kp = Kp + (size_t)(64 + sr) * DKD + sc;
        kreg0 = *(const uint4*)(kp); kreg1 = *(const uint4*)(kp + 8);
        const unsigned short* vp = Vtp + (size_t)sr * SEQ + 64 + sc;
        vreg0 = *(const uint4*)(vp); vreg1 = *(const uint4*)(vp + 8);
    }

    u32x2 pkE[4], bvE[4];          // even-tile P (bf16) and V frags, held to odd phase

#pragma unroll 1
    for (int p = 0; p < 16; ++p) {
        // ================= even phase: kt = 2p (buf 0) =================
        {
            const int kt = 2 * p;
            __syncthreads();
            {   // write prefetched tile kt+1 -> buf 1
                uint4* dk = (uint4*)(&KV[1][0][sr * PADW + sc]);
                dk[0] = kreg0; dk[1] = kreg1;
                uint4* dv = (uint4*)(&KV[1][1][sr * PADW + sc]);
                dv[0] = vreg0; dv[1] = vreg1;
            }
            if (kt + 2 < 32) {
                const unsigned short* kp = Kp + (size_t)((kt + 2) * 64 + sr) * DKD + sc;
                kreg0 = *(const uint4*)(kp); kreg1 = *(const uint4*)(kp + 8);
                const unsigned short* vp = Vtp + (size_t)sr * SEQ + (kt + 2) * 64 + sc;
                vreg0 = *(const uint4*)(vp); vreg1 = *(const uint4*)(vp + 8);
            }
            const unsigned short* Kc = &KV[0][0][0];
            const unsigned short* Vc = &KV[0][1][0];

            bf16x8 ak0 = *(const bf16x8*)(Kc + (w * 16 + lm) * PADW + kq * 8);
            bf16x8 ak1 = *(const bf16x8*)(Kc + (w * 16 + lm) * PADW + 32 + kq * 8);
            f32x4 s[4];
#pragma unroll
            for (int c = 0; c < 4; ++c) {
                s[c] = MFMA32(ak0, aq[c][0], Z4);
                s[c] = MFMA32(ak1, aq[c][1], s[c]);
            }
#pragma unroll
            for (int c = 0; c < 4; ++c) {
#pragma unroll
                for (int r = 0; r < 4; ++r) s[c][r] = EXP2(s[c][r]);
                ls[c] += (s[c][0] + s[c][1]) + (s[c][2] + s[c][3]);
                pkE[c].x = pack_bf2(s[c][0], s[c][1]);
                pkE[c].y = pack_bf2(s[c][2], s[c][3]);
            }
#pragma unroll
            for (int dj = 0; dj < 4; ++dj)
                bvE[dj] = __builtin_bit_cast(u32x2,
                    *(const bf16x4*)(Vc + (dj * 16 + lm) * PADW + w * 16 + kq * 4));
        }

        // ================= odd phase: kt = 2p+1 (buf 1) ================
        {
            const int kt = 2 * p + 1;
            __syncthreads();
            if (kt + 1 < 32) {   // write prefetched tile kt+1 -> buf 0
                uint4* dk = (uint4*)(&KV[0][0][sr * PADW + sc]);
                dk[0] = kreg0; dk[1] = kreg1;
                uint4* dv = (uint4*)(&KV[0][1][sr * PADW + sc]);
                dv[0] = vreg0; dv[1] = vreg1;
            }
            if (kt + 2 < 32) {
                const unsigned short* kp = Kp + (size_t)((kt + 2) * 64 + sr) * DKD + sc;
                kreg0 = *(const uint4*)(kp); kreg1 = *(const uint4*)(kp + 8);
                const unsigned short* vp = Vtp + (size_t)sr * SEQ + (kt + 2) * 64 + sc;
                vreg0 = *(const uint4*)(vp); vreg1 = *(const uint4*)(vp + 8);
            }
            const unsigned short* Kc = &KV[1][0][0];
            const unsigned short* Vc = &KV[1][1][0];

            bf16x8 ak0 = *(const bf16x8*)(Kc + (w * 16 + lm) * PADW + kq * 8);
            bf16x8 ak1 = *(const bf16x8*)(Kc + (w * 16 + lm) * PADW + 32 + kq * 8);
            f32x4 s[4];
#pragma unroll
            for (int c = 0; c < 4; ++c) {
                s[c] = MFMA32(ak0, aq[c][0], Z4);
                s[c] = MFMA32(ak1, aq[c][1], s[c]);
            }
            u32x2 pkO[4];
#pragma unroll
            for (int c = 0; c < 4; ++c) {
#pragma unroll
                for (int r = 0; r < 4; ++r) s[c][r] = EXP2(s[c][r]);
                ls[c] += (s[c][0] + s[c][1]) + (s[c][2] + s[c][3]);
                pkO[c].x = pack_bf2(s[c][0], s[c][1]);
                pkO[c].y = pack_bf2(s[c][2], s[c][3]);
            }

            // paired PV: K=32 over both tiles (k = kq*8 + tile*4 + r)
#pragma unroll
            for (int dj = 0; dj < 4; ++dj) {
                u32x2 bvO = __builtin_bit_cast(u32x2,
                    *(const bf16x4*)(Vc + (dj * 16 + lm) * PADW + w * 16 + kq * 4));
                u32x4 bw; bw.x = bvE[dj].x; bw.y = bvE[dj].y; bw.z = bvO.x; bw.w = bvO.y;
                bf16x8 bv = __builtin_bit_cast(bf16x8, bw);
#pragma unroll
                for (int c = 0; c < 4; ++c) {
                    u32x4 aw; aw.x = pkE[c].x; aw.y = pkE[c].y; aw.z = pkO[c].x; aw.w = pkO[c].y;
                    bf16x8 av = __builtin_bit_cast(bf16x8, aw);
                    o[c][dj] = MFMA32(av, bv, o[c][dj]);
                }
            }
        }
    }

    // ---------------- cross-wave reduction through retired KV LDS ----------
    __syncthreads();
    float* Lf = (float*)(&KV[0][0][0]);       // 9216 floats available

    // l: reduce over quads in-wave, write per-wave partials Lf[w*64 + q]
#pragma unroll
    for (int c = 0; c < 4; ++c) {
        float v = ls[c];
        v += __shfl_xor(v, 16);
        v += __shfl_xor(v, 32);
        if (kq == 0) Lf[w * 64 + c * 16 + lm] = v;
    }
    __syncthreads();

    // each thread computes linv for the q-row it will store (rq = t>>2)
    const int rq = t >> 2;                    // 0..63
    const int dq = (t & 3) * 8;               // d offset within 32-chunk
    float li = (Lf[rq] + Lf[64 + rq]) + (Lf[128 + rq] + Lf[192 + rq]);
#if __has_builtin(__builtin_amdgcn_rcpf)
    li = __builtin_amdgcn_rcpf(li);
#else
    li = 1.0f / li;
#endif
    __syncthreads();                          // l reads done before overwrite

    const int b = bh >> 4, h = bh & 15;
    // O: two passes of 32 d-columns; Lo[w][q=64][d'=32] stride 36 (=9216 floats)
#pragma unroll
    for (int p = 0; p < 2; ++p) {
#pragma unroll
        for (int c = 0; c < 4; ++c)
#pragma unroll
            for (int djh = 0; djh < 2; ++djh) {
                const int dj = 2 * p + djh;
#pragma unroll
                for (int r = 0; r < 4; ++r)
                    Lf[(w * 64 + c * 16 + kq * 4 + r) * 36 + djh * 16 + lm] = o[c][dj][r];
            }
        __syncthreads();
        f32x4 a0 = Z4, a1 = Z4;
#pragma unroll
        for (int wp = 0; wp < 4; ++wp) {
            a0 += *(const f32x4*)(Lf + (wp * 64 + rq) * 36 + dq);
            a1 += *(const f32x4*)(Lf + (wp * 64 + rq) * 36 + dq + 4);
        }
        uint4 outv;
        outv.x = pack_bf2(a0[0] * li, a0[1] * li);
        outv.y = pack_bf2(a0[2] * li, a0[3] * li);
        outv.z = pack_bf2(a1[0] * li, a1[1] * li);
        outv.w = pack_bf2(a1[2] * li, a1[3] * li);
        *(uint4*)(Og + (((size_t)(b * SEQ + qb * 64 + rq)) * NHEAD + h) * DKD + p * 32 + dq) = outv;
        __syncthreads();
    }
}

// ---------------------------------------------------------------- launcher
extern "C" void kernel_launch(void* const* d_in, const int* in_sizes, int n_in,
                              void* d_out, int out_size, void* d_ws, size_t ws_size,
                              hipStream_t stream) {
    const float* x  = (const float*)d_in[0];
    const float* Wq = (const float*)d_in[1];
    const float* Wk = (const float*)d_in[2];
    const float* Wv = (const float*)d_in[3];
    const float* Wo = (const float*)d_in[4];
    const float* bo = (const float*)d_in[5];
    float* out = (float*)d_out;

    unsigned short* ws = (unsigned short*)d_ws;
    unsigned short* Xb   = ws;                       // [4096][1024]
    unsigned short* Wqkv = ws + 4194304;             // [3072][1024] (Wq|Wk|Wv)
    unsigned short* Wob  = ws + 7340032;             // [1024][1024]
    unsigned short* QKV  = ws + 8388608;             // Q,K:[b,h,s,d]; V:[b,h,d,s]
    unsigned short* Ob   = ws + 20971520;            // [4096][1024] = [b,s,h,d]

    cast_all<<<8192, 256, 0, stream>>>(x, Wq, Wk, Wv, Wo, Xb, Wqkv, Wob);
    gemm_bt<0, 128><<<dim3(32, 24), 256, 0, stream>>>(Xb, Wqkv, QKV, nullptr, nullptr);
    attn_kernel<<<1024, 256, 0, stream>>>(QKV, QKV + 4194304, QKV + 8388608, Ob);
    gemm_bt<1, 64><<<dim3(32, 16), 256, 0, stream>>>(Ob, Wob, nullptr, out, bo);
}